// Round 5
// baseline (615.673 us; speedup 1.0000x reference)
//
#include <hip/hip_runtime.h>

#define NN 100000
#define NE 1600000
#define NBK 196       // ceil(100000/512) dst buckets (512 nodes each)
#define CAP 10240     // per-bucket edge capacity
#define EPB 8192      // edges per block in k_bin
#define NWAVES 4096   // fixed wave count for k_gmm/k_mlp (1024 blocks x 4 waves)

// ---------------- pass 1: bin edges by dst>>9, packed (src<<9)|dst_local ----------------
__global__ __launch_bounds__(256) void k_bin(const int* __restrict__ src,
                                             const int* __restrict__ dst,
                                             int* __restrict__ gcnt,
                                             unsigned int* __restrict__ binned, int E) {
  __shared__ int bcnt[256];
  const int t = threadIdx.x;
  const int e0 = blockIdx.x * EPB;
  bcnt[t] = 0;
  __syncthreads();
  for (int i = 0; i < EPB; i += 256) {
    int e = e0 + i + t;
    if (e < E) atomicAdd(&bcnt[dst[e] >> 9], 1);
  }
  __syncthreads();
  if (t < NBK) {
    int c = bcnt[t];
    bcnt[t] = c ? atomicAdd(&gcnt[t], c) : 0;
  }
  __syncthreads();
  for (int i = 0; i < EPB; i += 256) {
    int e = e0 + i + t;
    if (e < E) {
      int d = dst[e];
      int b = d >> 9;
      int pos = atomicAdd(&bcnt[b], 1);
      if (pos < CAP) binned[(size_t)b * CAP + pos] = ((unsigned int)src[e] << 9) | (d & 511);
    }
  }
}

// ---------------- pass 2: per-bucket local CSR (block-local writes) ----------------
__global__ __launch_bounds__(512) void k_csr(const unsigned int* __restrict__ binned,
                                             const int* __restrict__ gcnt,
                                             int* __restrict__ rowbeg,
                                             int* __restrict__ rowend,
                                             int* __restrict__ eidx, int N) {
  __shared__ int hist[512];
  __shared__ int cur[512];
  const int t = threadIdx.x;
  const int b = blockIdx.x;
  const size_t base = (size_t)b * CAP;
  int cnt = gcnt[b];
  if (cnt > CAP) cnt = CAP;
  hist[t] = 0;
  __syncthreads();
  for (int e = t; e < cnt; e += 512) atomicAdd(&hist[binned[base + e] & 511], 1);
  __syncthreads();
  const int own = hist[t];
  for (int o = 1; o < 512; o <<= 1) {
    int x = (t >= o) ? hist[t - o] : 0;
    __syncthreads();
    hist[t] += x;
    __syncthreads();
  }
  const int incl = hist[t];
  const int excl = incl - own;
  const int node = b * 512 + t;
  if (node < N) {
    rowbeg[node] = (int)base + excl;
    rowend[node] = (int)base + incl;
  }
  cur[t] = excl;
  __syncthreads();
  for (int e = t; e < cnt; e += 512) {
    unsigned int pk = binned[base + e];
    int pos = atomicAdd(&cur[pk & 511], 1);
    eidx[base + pos] = (int)(pk >> 9);
  }
}

// ------- k_red: reduce per-wave column partials -> BN affine LUT -------
__global__ __launch_bounds__(256) void k_red(const float* __restrict__ P, int nblk,
                                             const float* __restrict__ g,
                                             const float* __restrict__ bt,
                                             double invN, float* __restrict__ aff) {
  const int c = blockIdx.x;  // 0..63 (one column per block)
  const int t = threadIdx.x;
  double as = 0.0, aq = 0.0;
  for (int i = t; i < nblk; i += 256) {
    as += (double)P[(size_t)i * 128 + c];
    aq += (double)P[(size_t)i * 128 + 64 + c];
  }
  __shared__ double rs[256], rq[256];
  rs[t] = as;
  rq[t] = aq;
  __syncthreads();
  for (int o = 128; o > 0; o >>= 1) {
    if (t < o) {
      rs[t] += rs[t + o];
      rq[t] += rq[t + o];
    }
    __syncthreads();
  }
  if (t == 0) {
    double mu = rs[0] * invN;
    double var = rq[0] * invN - mu * mu;
    double ai = (double)g[c] / sqrt(var + 1e-5);
    aff[c] = (float)ai;
    aff[64 + c] = (float)((double)bt[c] - ai * mu);
  }
}

__device__ __forceinline__ float rdl(float v, int l) {
  return __int_as_float(__builtin_amdgcn_readlane(__float_as_int(v), l));
}

// ========== fused gather + GEMM1: Z = (gathered,affined A) @ W1 + b1, + stats(Z) ==========
// Wave = 4 consecutive nodes; 16-lane group per node. Gather: each group sums its
// node's row + neighbor rows (float4/lane, coalesced 256B per row, unroll-4 -> 16
// rows in flight per wave). Result lands in exactly the layout the readlane-GEMM
// wants (lane j*16+i holds row j elements 4i..4i+3). No LDS, no barriers.
template <bool XFORM>
__global__ __launch_bounds__(256) void k_gmm(const float* __restrict__ In,
                                             const float* __restrict__ aff,
                                             const int* __restrict__ rowbeg,
                                             const int* __restrict__ rowend,
                                             const int* __restrict__ eidx,
                                             const float* __restrict__ W,
                                             const float* __restrict__ b,
                                             float* __restrict__ Out,
                                             float* __restrict__ P, int N) {
  const int lane = threadIdx.x & 63;
  const int li = lane & 15;
  const int wid = (blockIdx.x * 256 + threadIdx.x) >> 6;
  const int G = N >> 2;  // N % 4 == 0

  float w[64];
#pragma unroll
  for (int k = 0; k < 64; ++k) w[k] = W[k * 64 + lane];
  const float bias = b[lane];

  float4 fa = make_float4(1.f, 1.f, 1.f, 1.f);
  float4 fd = make_float4(0.f, 0.f, 0.f, 0.f);
  if (XFORM) {
    fa = *(const float4*)(aff + li * 4);
    fd = *(const float4*)(aff + 64 + li * 4);
  }

  float sc = 0.f, qc = 0.f;

  for (int g = wid; g < G; g += NWAVES) {
    const int node = g * 4 + (lane >> 4);
    const int beg = rowbeg[node], end = rowend[node];
    float4 s = *(const float4*)(In + (size_t)node * 64 + li * 4);  // self (eps=0)
    float4 s2 = make_float4(0.f, 0.f, 0.f, 0.f);
    int i = beg;
    for (; i + 4 <= end; i += 4) {
      const int e0 = eidx[i], e1 = eidx[i + 1], e2 = eidx[i + 2], e3 = eidx[i + 3];
      const float4 v0 = *(const float4*)(In + (size_t)e0 * 64 + li * 4);
      const float4 v1 = *(const float4*)(In + (size_t)e1 * 64 + li * 4);
      const float4 v2 = *(const float4*)(In + (size_t)e2 * 64 + li * 4);
      const float4 v3 = *(const float4*)(In + (size_t)e3 * 64 + li * 4);
      s.x += v0.x + v1.x; s.y += v0.y + v1.y; s.z += v0.z + v1.z; s.w += v0.w + v1.w;
      s2.x += v2.x + v3.x; s2.y += v2.y + v3.y; s2.z += v2.z + v3.z; s2.w += v2.w + v3.w;
    }
    for (; i < end; ++i) {
      const float4 v = *(const float4*)(In + (size_t)eidx[i] * 64 + li * 4);
      s.x += v.x; s.y += v.y; s.z += v.z; s.w += v.w;
    }
    s.x += s2.x; s.y += s2.y; s.z += s2.z; s.w += s2.w;
    if (XFORM) {
      const float cnt = (float)(end - beg + 1);
      s.x = fmaf(fa.x, s.x, cnt * fd.x);
      s.y = fmaf(fa.y, s.y, cnt * fd.y);
      s.z = fmaf(fa.z, s.z, cnt * fd.z);
      s.w = fmaf(fa.w, s.w, cnt * fd.w);
    }
    const float a4[4] = {s.x, s.y, s.z, s.w};

    float acc0 = bias, acc1 = bias, acc2 = bias, acc3 = bias;
#pragma unroll
    for (int k = 0; k < 64; ++k) {
      const float ak = a4[k & 3];
      const int sl = k >> 2;
      acc0 = fmaf(rdl(ak, sl), w[k], acc0);
      acc1 = fmaf(rdl(ak, 16 + sl), w[k], acc1);
      acc2 = fmaf(rdl(ak, 32 + sl), w[k], acc2);
      acc3 = fmaf(rdl(ak, 48 + sl), w[k], acc3);
    }
    const int r0 = g * 4;
    Out[(size_t)(r0 + 0) * 64 + lane] = acc0;
    Out[(size_t)(r0 + 1) * 64 + lane] = acc1;
    Out[(size_t)(r0 + 2) * 64 + lane] = acc2;
    Out[(size_t)(r0 + 3) * 64 + lane] = acc3;
    sc += acc0 + acc1 + acc2 + acc3;
    qc = fmaf(acc0, acc0, qc);
    qc = fmaf(acc1, acc1, qc);
    qc = fmaf(acc2, acc2, qc);
    qc = fmaf(acc3, acc3, qc);
  }
  P[(size_t)wid * 128 + lane] = sc;
  P[(size_t)wid * 128 + 64 + lane] = qc;
}

// ========== register-resident GEMM2 ==========
// MODE 1: relu(out), store, stats(relu)   [inner layers]
// MODE 3: log_softmax(out) -> store        [final layer]
template <int OUTC, int MODE>
__global__ __launch_bounds__(256) void k_mlp(const float* __restrict__ In,
                                             const float* __restrict__ aff,
                                             const float* __restrict__ W,
                                             const float* __restrict__ b,
                                             float* __restrict__ Out,
                                             float* __restrict__ P, int N) {
  const int lane = threadIdx.x & 63;
  const int wid = (blockIdx.x * 256 + threadIdx.x) >> 6;
  const int nw = NWAVES;
  const int G = N >> 2;

  const int cc = (lane < OUTC) ? lane : 0;
  float w[64];
#pragma unroll
  for (int k = 0; k < 64; ++k) w[k] = W[k * OUTC + cc];
  const float bias = b[cc];

  const float4 fa = *(const float4*)(aff + (lane & 15) * 4);
  const float4 fd = *(const float4*)(aff + 64 + (lane & 15) * 4);

  float sc = 0.f, qc = 0.f;

  int g = wid;
  float4 av = make_float4(0.f, 0.f, 0.f, 0.f);
  if (g < G) av = *(const float4*)(In + (size_t)g * 256 + lane * 4);
  for (; g < G; g += nw) {
    const int gn = g + nw;
    float4 nx = make_float4(0.f, 0.f, 0.f, 0.f);
    if (gn < G) nx = *(const float4*)(In + (size_t)gn * 256 + lane * 4);

    float4 v = av;
    v.x = fmaxf(fmaf(fa.x, v.x, fd.x), 0.f);
    v.y = fmaxf(fmaf(fa.y, v.y, fd.y), 0.f);
    v.z = fmaxf(fmaf(fa.z, v.z, fd.z), 0.f);
    v.w = fmaxf(fmaf(fa.w, v.w, fd.w), 0.f);
    const float a4[4] = {v.x, v.y, v.z, v.w};

    float acc0 = bias, acc1 = bias, acc2 = bias, acc3 = bias;
#pragma unroll
    for (int k = 0; k < 64; ++k) {
      const float ak = a4[k & 3];
      const int sl = k >> 2;
      acc0 = fmaf(rdl(ak, sl), w[k], acc0);
      acc1 = fmaf(rdl(ak, 16 + sl), w[k], acc1);
      acc2 = fmaf(rdl(ak, 32 + sl), w[k], acc2);
      acc3 = fmaf(rdl(ak, 48 + sl), w[k], acc3);
    }

    const int r0 = g * 4;
    if (MODE == 1) {
      const float o0 = fmaxf(acc0, 0.f), o1 = fmaxf(acc1, 0.f);
      const float o2 = fmaxf(acc2, 0.f), o3 = fmaxf(acc3, 0.f);
      Out[(size_t)(r0 + 0) * OUTC + lane] = o0;
      Out[(size_t)(r0 + 1) * OUTC + lane] = o1;
      Out[(size_t)(r0 + 2) * OUTC + lane] = o2;
      Out[(size_t)(r0 + 3) * OUTC + lane] = o3;
      sc += o0 + o1 + o2 + o3;
      qc = fmaf(o0, o0, qc);
      qc = fmaf(o1, o1, qc);
      qc = fmaf(o2, o2, qc);
      qc = fmaf(o3, o3, qc);
    } else {  // MODE 3: log_softmax over OUTC cols (lanes >= OUTC masked out)
      float m0 = (lane < OUTC) ? acc0 : -1e30f;
      float m1 = (lane < OUTC) ? acc1 : -1e30f;
      float m2 = (lane < OUTC) ? acc2 : -1e30f;
      float m3 = (lane < OUTC) ? acc3 : -1e30f;
#pragma unroll
      for (int off = 32; off; off >>= 1) {
        m0 = fmaxf(m0, __shfl_xor(m0, off));
        m1 = fmaxf(m1, __shfl_xor(m1, off));
        m2 = fmaxf(m2, __shfl_xor(m2, off));
        m3 = fmaxf(m3, __shfl_xor(m3, off));
      }
      float s0 = (lane < OUTC) ? expf(acc0 - m0) : 0.f;
      float s1 = (lane < OUTC) ? expf(acc1 - m1) : 0.f;
      float s2 = (lane < OUTC) ? expf(acc2 - m2) : 0.f;
      float s3 = (lane < OUTC) ? expf(acc3 - m3) : 0.f;
#pragma unroll
      for (int off = 32; off; off >>= 1) {
        s0 += __shfl_xor(s0, off);
        s1 += __shfl_xor(s1, off);
        s2 += __shfl_xor(s2, off);
        s3 += __shfl_xor(s3, off);
      }
      if (lane < OUTC) {
        Out[(size_t)(r0 + 0) * OUTC + lane] = acc0 - (m0 + logf(s0));
        Out[(size_t)(r0 + 1) * OUTC + lane] = acc1 - (m1 + logf(s1));
        Out[(size_t)(r0 + 2) * OUTC + lane] = acc2 - (m2 + logf(s2));
        Out[(size_t)(r0 + 3) * OUTC + lane] = acc3 - (m3 + logf(s3));
      }
    }
    av = nx;
  }

  if (MODE == 1) {
    P[(size_t)wid * 128 + lane] = sc;
    P[(size_t)wid * 128 + 64 + lane] = qc;
  }
}

extern "C" void kernel_launch(void* const* d_in, const int* in_sizes, int n_in,
                              void* d_out, int out_size, void* d_ws, size_t ws_size,
                              hipStream_t stream) {
  const float* x = (const float*)d_in[0];
  const int* src = (const int*)d_in[1];
  const int* dst = (const int*)d_in[2];
  const float *W1[3], *b1[3], *g[3], *bt[3], *W2[3], *b2[3];
  for (int i = 0; i < 3; ++i) {
    W1[i] = (const float*)d_in[3 + i * 6 + 0];
    b1[i] = (const float*)d_in[3 + i * 6 + 1];
    g[i] = (const float*)d_in[3 + i * 6 + 2];
    bt[i] = (const float*)d_in[3 + i * 6 + 3];
    W2[i] = (const float*)d_in[3 + i * 6 + 4];
    b2[i] = (const float*)d_in[3 + i * 6 + 5];
  }
  const float* bng[2] = {(const float*)d_in[21], (const float*)d_in[23]};
  const float* bnb[2] = {(const float*)d_in[22], (const float*)d_in[24]};

  const int N = NN, E = NE;
  const size_t N64 = (size_t)N * 64;
  const int gmlp = NWAVES / 4;     // 1024 blocks (4 waves each)

  // workspace layout (~72 MB)
  char* p = (char*)d_ws;
  float* B = (float*)p; p += N64 * 4;            // z buffer
  float* C = (float*)p; p += N64 * 4;            // relu(h) buffer
  int* gcnt = (int*)p; p += 256 * 4;             // bucket counters (memset)
  float* aff = (float*)p; p += 128 * 4;          // BN affine LUT (a[64], d[64])
  float* P = (float*)p; p += (size_t)NWAVES * 128 * 4;  // per-wave column partials (2MB)
  int* rowbeg = (int*)p; p += (size_t)N * 4;
  int* rowend = (int*)p; p += (size_t)N * 4;
  unsigned int* binned = (unsigned int*)p; p += (size_t)NBK * CAP * 4;
  int* eidx = (int*)p; p += (size_t)NBK * CAP * 4;

  const double invN = 1.0 / (double)N;

  hipMemsetAsync(gcnt, 0, 256 * 4, stream);

  // ---- CSR build (bucketed counting sort, block-local writes) ----
  k_bin<<<(E + EPB - 1) / EPB, 256, 0, stream>>>(src, dst, gcnt, binned, E);
  k_csr<<<NBK, 512, 0, stream>>>(binned, gcnt, rowbeg, rowend, eidx, N);

  // ---- layer 0 (input = x, no affine on gather) ----
  k_gmm<false><<<gmlp, 256, 0, stream>>>(x, nullptr, rowbeg, rowend, eidx, W1[0], b1[0], B, P, N);
  k_red<<<64, 256, 0, stream>>>(P, NWAVES, g[0], bt[0], invN, aff);
  k_mlp<64, 1><<<gmlp, 256, 0, stream>>>(B, aff, W2[0], b2[0], C, P, N);
  k_red<<<64, 256, 0, stream>>>(P, NWAVES, bng[0], bnb[0], invN, aff);

  // ---- layer 1 ----
  k_gmm<true><<<gmlp, 256, 0, stream>>>(C, aff, rowbeg, rowend, eidx, W1[1], b1[1], B, P, N);
  k_red<<<64, 256, 0, stream>>>(P, NWAVES, g[1], bt[1], invN, aff);
  k_mlp<64, 1><<<gmlp, 256, 0, stream>>>(B, aff, W2[1], b2[1], C, P, N);
  k_red<<<64, 256, 0, stream>>>(P, NWAVES, bng[1], bnb[1], invN, aff);

  // ---- layer 2 (final: fused log_softmax) ----
  k_gmm<true><<<gmlp, 256, 0, stream>>>(C, aff, rowbeg, rowend, eidx, W1[2], b1[2], B, P, N);
  k_red<<<64, 256, 0, stream>>>(P, NWAVES, g[2], bt[2], invN, aff);
  k_mlp<40, 3><<<gmlp, 256, 0, stream>>>(B, aff, W2[2], b2[2], (float*)d_out, nullptr, N);
}